// Round 6
// baseline (83.028 us; speedup 1.0000x reference)
//
#include <hip/hip_runtime.h>

#define NN 512
#define NWD 128
#define NSLICES 96                      // B*P*Q
#define NROWS (NSLICES * NN)            // 49152
#define NBLOCKS 768                     // 8 blocks per slice
#define ALPHA 0.2f

__device__ __forceinline__ float lrelu(float x) {
    return x > 0.f ? x : ALPHA * x;
}

// One kernel, slice-local producer/consumer pipeline (no grid barrier):
//   Phase A: wa1/wa2 = W@a1, W@a2 (coalesced, per-block redundant) -> LDS
//   Phase B: s1 (LDS), s2 for this block's OWN 64 rows -> agent-scope stores
//   publish: __syncthreads (drains stores) + atomicAdd(slice counter)
//   spin:    until slice counter == 8 (all 768 blocks co-resident: 3072 waves
//            << 8192-wave device capacity at this VGPR/LDS -> no deadlock)
//   Phase C: stream own 64 demand rows -> out. s2 read via agent-scope atomic
//            loads (coherent across XCDs and across graph replays).
//   Softmax max-subtraction dropped: |e| <= ~15 so exp() cannot overflow f32.
__global__ __launch_bounds__(256) void fused_kernel(const float* __restrict__ demand,
                                                    const float* __restrict__ st,
                                                    const float* __restrict__ W,
                                                    const float* __restrict__ a,
                                                    float* __restrict__ s2g,
                                                    int* __restrict__ cnt,
                                                    float* __restrict__ out) {
    __shared__ float wa1[NWD];
    __shared__ float wa2[NWD];
    __shared__ float s1L[64];

    const int t = threadIdx.x;
    const int wid = t >> 6;
    const int lane = t & 63;
    const int l5 = lane & 31;       // position within half-wave
    const int half = lane >> 5;     // 0: even row of pair, 1: odd row

    // XCD-chunked bijective remap: a slice's 8 sibling blocks land on one XCD.
    const int p = blockIdx.x;
    const int b = (p & 7) * (NBLOCKS / 8) + (p >> 3);
    const int slice = b >> 3;
    const int rowblk = (b & 7) * 64;
    const long gbase = (long)slice * NN + rowblk;   // first global row of block

    // ---- Phase A: coalesced wa (proven R5 code) ----
    {
        const float4 a1v = *reinterpret_cast<const float4*>(a + l5 * 4);
        const float4 a2v = *reinterpret_cast<const float4*>(a + NWD + l5 * 4);
        #pragma unroll
        for (int i = 0; i < 16; ++i) {
            const int k = wid * 32 + i * 2;   // W row pair (k, k+1)
            const float4 wv = *reinterpret_cast<const float4*>(W + (long)k * NWD + lane * 4);
            float p1 = wv.x * a1v.x + wv.y * a1v.y + wv.z * a1v.z + wv.w * a1v.w;
            float p2 = wv.x * a2v.x + wv.y * a2v.y + wv.z * a2v.z + wv.w * a2v.w;
            #pragma unroll
            for (int off = 16; off > 0; off >>= 1) {
                p1 += __shfl_xor(p1, off);
                p2 += __shfl_xor(p2, off);
            }
            if (l5 == 0) { wa1[k + half] = p1; wa2[k + half] = p2; }
        }
    }
    __syncthreads();

    // ---- Phase B: s1,s2 for own 64 rows (wave w covers local rows [16w,16w+16)) ----
    {
        const float4 w1v = *reinterpret_cast<const float4*>(&wa1[l5 * 4]);
        const float4 w2v = *reinterpret_cast<const float4*>(&wa2[l5 * 4]);
        #pragma unroll
        for (int i = 0; i < 8; ++i) {
            const int rp = wid * 16 + i * 2;       // local row pair
            const float4 f = *reinterpret_cast<const float4*>(st + (gbase + rp) * NWD + lane * 4);
            float p1 = f.x * w1v.x + f.y * w1v.y + f.z * w1v.z + f.w * w1v.w;
            float p2 = f.x * w2v.x + f.y * w2v.y + f.z * w2v.z + f.w * w2v.w;
            #pragma unroll
            for (int off = 16; off > 0; off >>= 1) {
                p1 += __shfl_xor(p1, off);
                p2 += __shfl_xor(p2, off);
            }
            if (l5 == 0) {
                s1L[rp + half] = p1;
                __hip_atomic_store(&s2g[gbase + rp + half], p2,
                                   __ATOMIC_RELAXED, __HIP_MEMORY_SCOPE_AGENT);
            }
        }
    }
    __syncthreads();               // drains all waves' s2 stores (vmcnt 0)

    // ---- publish + spin (slice-local sync) ----
    if (t == 0) {
        __threadfence();
        atomicAdd(&cnt[slice], 1);
        while (__hip_atomic_load(&cnt[slice], __ATOMIC_ACQUIRE,
                                 __HIP_MEMORY_SCOPE_AGENT) < 8) {
            __builtin_amdgcn_s_sleep(4);
        }
    }
    __syncthreads();

    // ---- Phase C: stream own 64 rows (wave w: local rows [16w,16w+16)) ----
    const int c0 = lane * 4;
    const int c1 = 256 + lane * 4;
    const float* s2s = s2g + (long)slice * NN;
    float sa[4], sb[4];
    #pragma unroll
    for (int k = 0; k < 4; ++k)
        sa[k] = __hip_atomic_load(&s2s[c0 + k], __ATOMIC_RELAXED, __HIP_MEMORY_SCOPE_AGENT);
    #pragma unroll
    for (int k = 0; k < 4; ++k)
        sb[k] = __hip_atomic_load(&s2s[c1 + k], __ATOMIC_RELAXED, __HIP_MEMORY_SCOPE_AGENT);

    for (int i = 0; i < 16; ++i) {
        const int row = wid * 16 + i;          // local row
        const long g = gbase + row;            // global row
        const float s1i = s1L[row];

        float pv[8];
        #pragma unroll
        for (int k = 0; k < 4; ++k) pv[k] = __expf(lrelu(s1i + sa[k]));
        #pragma unroll
        for (int k = 0; k < 4; ++k) pv[4 + k] = __expf(lrelu(s1i + sb[k]));

        float sum = 0.f;
        #pragma unroll
        for (int k = 0; k < 8; ++k) sum += pv[k];
        #pragma unroll
        for (int off = 32; off > 0; off >>= 1) sum += __shfl_xor(sum, off);
        const float inv = 1.f / sum;

        const float* drow = demand + g * NN;
        const float4 d0 = *reinterpret_cast<const float4*>(drow + c0);
        const float4 d1 = *reinterpret_cast<const float4*>(drow + c1);

        float4 o0, o1;
        o0.x = lrelu(d0.x * pv[0] * inv); o0.y = lrelu(d0.y * pv[1] * inv);
        o0.z = lrelu(d0.z * pv[2] * inv); o0.w = lrelu(d0.w * pv[3] * inv);
        o1.x = lrelu(d1.x * pv[4] * inv); o1.y = lrelu(d1.y * pv[5] * inv);
        o1.z = lrelu(d1.z * pv[6] * inv); o1.w = lrelu(d1.w * pv[7] * inv);

        float* orow = out + g * NN;
        *reinterpret_cast<float4*>(orow + c0) = o0;
        *reinterpret_cast<float4*>(orow + c1) = o1;
    }
}

extern "C" void kernel_launch(void* const* d_in, const int* in_sizes, int n_in,
                              void* d_out, int out_size, void* d_ws, size_t ws_size,
                              hipStream_t stream) {
    const float* demand  = (const float*)d_in[0];
    const float* st_feat = (const float*)d_in[1];
    const float* W       = (const float*)d_in[2];
    const float* a       = (const float*)d_in[3];
    float* out = (float*)d_out;

    float* s2g = (float*)d_ws;                 // NROWS floats
    int*   cnt = (int*)(s2g + NROWS);          // NSLICES ints

    hipMemsetAsync(cnt, 0, NSLICES * sizeof(int), stream);
    fused_kernel<<<NBLOCKS, 256, 0, stream>>>(demand, st_feat, W, a, s2g, cnt, out);
}

// Round 7
// 45.331 us; speedup vs baseline: 1.8316x; 1.8316x over previous
//
#include <hip/hip_runtime.h>

#define NN 512
#define NWD 128
#define NSLICES 96                      // B*P*Q
#define NROWS (NSLICES * NN)            // 49152
#define ALPHA 0.2f

__device__ __forceinline__ float lrelu(float x) {
    return x > 0.f ? x : ALPHA * x;
}

// k0: wa1 = W@a1, wa2 = W@a2 -> global ws (256 floats).
// 16 blocks x 256 threads; each wave does ONE coalesced row-pair butterfly:
// lanes read a contiguous 1 KB (rows k, k+1 of W); half-wave 5-round reduce.
__global__ __launch_bounds__(256) void wa_kernel(const float* __restrict__ W,
                                                 const float* __restrict__ a,
                                                 float* __restrict__ wa) {
    const int t = threadIdx.x;
    const int wid = t >> 6;
    const int lane = t & 63;
    const int l5 = lane & 31;
    const int half = lane >> 5;

    const int k = (blockIdx.x * 4 + wid) * 2;      // W row pair (k, k+1), k in [0,128)
    const float4 a1v = *reinterpret_cast<const float4*>(a + l5 * 4);
    const float4 a2v = *reinterpret_cast<const float4*>(a + NWD + l5 * 4);
    const float4 wv  = *reinterpret_cast<const float4*>(W + (long)k * NWD + lane * 4);

    float p1 = wv.x * a1v.x + wv.y * a1v.y + wv.z * a1v.z + wv.w * a1v.w;
    float p2 = wv.x * a2v.x + wv.y * a2v.y + wv.z * a2v.z + wv.w * a2v.w;
    #pragma unroll
    for (int off = 16; off > 0; off >>= 1) {
        p1 += __shfl_xor(p1, off);
        p2 += __shfl_xor(p2, off);
    }
    if (l5 == 0) {
        wa[k + half] = p1;              // wa1
        wa[NWD + k + half] = p2;        // wa2
    }
}

// k1: s1[g], s2[g] for all rows. 768 blocks x 64 rows; wa fragments read
// directly from global (L2-hot broadcast); no LDS, no syncthreads.
// Each wave: 8 iters x 2 rows, float4 loads (16 B/lane), 5-round butterfly.
__global__ __launch_bounds__(256) void s_kernel(const float* __restrict__ st,
                                                const float* __restrict__ wa,
                                                float* __restrict__ s1,
                                                float* __restrict__ s2) {
    const int t = threadIdx.x;
    const int wid = t >> 6;
    const int lane = t & 63;
    const int l5 = lane & 31;
    const int half = lane >> 5;

    const float4 w1v = *reinterpret_cast<const float4*>(wa + l5 * 4);
    const float4 w2v = *reinterpret_cast<const float4*>(wa + NWD + l5 * 4);
    const long blockbase = (long)blockIdx.x * 64;

    #pragma unroll
    for (int i = 0; i < 8; ++i) {
        const long rowpair = blockbase + (long)wid * 16 + i * 2;
        const float4 f = *reinterpret_cast<const float4*>(st + rowpair * NWD + lane * 4);
        float p1 = f.x * w1v.x + f.y * w1v.y + f.z * w1v.z + f.w * w1v.w;
        float p2 = f.x * w2v.x + f.y * w2v.y + f.z * w2v.z + f.w * w2v.w;
        #pragma unroll
        for (int off = 16; off > 0; off >>= 1) {
            p1 += __shfl_xor(p1, off);
            p2 += __shfl_xor(p2, off);
        }
        if (l5 == 0) {
            s1[rowpair + half] = p1;
            s2[rowpair + half] = p2;
        }
    }
}

// k2: streaming kernel. One wave per row; 8 cols/lane (2x float4).
// No row-max: |s1|,|s2| <= ~7 so e <= ~15, exp(e) <= 1.2e6 -- safe in f32
// (validated in R6: identical absmax with and without max subtraction).
__global__ __launch_bounds__(256) void main_kernel(const float* __restrict__ demand,
                                                   const float* __restrict__ s1,
                                                   const float* __restrict__ s2,
                                                   float* __restrict__ out) {
    const int wid = threadIdx.x >> 6;
    const int lane = threadIdx.x & 63;
    const long g = (long)blockIdx.x * 4 + wid;   // global row
    const long slice = g >> 9;
    const float s1i = s1[g];
    const float* s2s = s2 + slice * NN;

    const int c0 = lane * 4;
    const int c1 = 256 + lane * 4;
    const float4 sa = *reinterpret_cast<const float4*>(s2s + c0);
    const float4 sb = *reinterpret_cast<const float4*>(s2s + c1);

    float pv[8];
    pv[0] = __expf(lrelu(s1i + sa.x));
    pv[1] = __expf(lrelu(s1i + sa.y));
    pv[2] = __expf(lrelu(s1i + sa.z));
    pv[3] = __expf(lrelu(s1i + sa.w));
    pv[4] = __expf(lrelu(s1i + sb.x));
    pv[5] = __expf(lrelu(s1i + sb.y));
    pv[6] = __expf(lrelu(s1i + sb.z));
    pv[7] = __expf(lrelu(s1i + sb.w));

    float sum = 0.f;
    #pragma unroll
    for (int k = 0; k < 8; ++k) sum += pv[k];
    #pragma unroll
    for (int off = 32; off > 0; off >>= 1) sum += __shfl_xor(sum, off);
    const float inv = 1.f / sum;

    const float* drow = demand + g * NN;
    const float4 d0 = *reinterpret_cast<const float4*>(drow + c0);
    const float4 d1 = *reinterpret_cast<const float4*>(drow + c1);

    float4 o0, o1;
    o0.x = lrelu(d0.x * pv[0] * inv); o0.y = lrelu(d0.y * pv[1] * inv);
    o0.z = lrelu(d0.z * pv[2] * inv); o0.w = lrelu(d0.w * pv[3] * inv);
    o1.x = lrelu(d1.x * pv[4] * inv); o1.y = lrelu(d1.y * pv[5] * inv);
    o1.z = lrelu(d1.z * pv[6] * inv); o1.w = lrelu(d1.w * pv[7] * inv);

    float* orow = out + g * NN;
    *reinterpret_cast<float4*>(orow + c0) = o0;
    *reinterpret_cast<float4*>(orow + c1) = o1;
}

extern "C" void kernel_launch(void* const* d_in, const int* in_sizes, int n_in,
                              void* d_out, int out_size, void* d_ws, size_t ws_size,
                              hipStream_t stream) {
    const float* demand  = (const float*)d_in[0];
    const float* st_feat = (const float*)d_in[1];
    const float* W       = (const float*)d_in[2];
    const float* a       = (const float*)d_in[3];
    float* out = (float*)d_out;

    float* wa = (float*)d_ws;                  // 256 floats
    float* s1 = wa + 2 * NWD;                  // NROWS floats
    float* s2 = s1 + NROWS;                    // NROWS floats

    wa_kernel<<<16, 256, 0, stream>>>(W, a, wa);
    s_kernel<<<NROWS / 64, 256, 0, stream>>>(st_feat, wa, s1, s2);
    main_kernel<<<NROWS / 4, 256, 0, stream>>>(demand, s1, s2, out);
}